// Round 6
// baseline (84.888 us; speedup 1.0000x reference)
//
#include <hip/hip_runtime.h>
#include <hip/hip_bf16.h>
#include <stdint.h>

#define B_ 8
#define C_ 2048
#define E_ 1024
#define H_ 128
#define M_ (B_*C_)      // 16384 rows total
#define SLOTS_B 144     // chunks per batch: sum_j ceil((j+1)/4), j<32

typedef __attribute__((ext_vector_type(8))) short bf16x8;
typedef __attribute__((ext_vector_type(4))) float f32x4;

__device__ __forceinline__ unsigned short f2bf(float f) {
    union { float f; unsigned int u; } v; v.f = f;
    unsigned int u = v.u;
    u += 0x7fff + ((u >> 16) & 1);   // RNE
    return (unsigned short)(u >> 16);
}
__device__ __forceinline__ float bf2f(unsigned short u) {
    union { unsigned int i; float f; } v; v.i = ((unsigned int)u) << 16; return v.f;
}

#define GLOAD_LDS16(g, l) \
    __builtin_amdgcn_global_load_lds((const __attribute__((address_space(1))) void*)(g), \
                                     (__attribute__((address_space(3))) void*)(l), 16, 0, 0)

// -------- W -> fragment-ordered bf16: WT2[w][g*128 + h] = 16B granule -------
// granule (g,h) holds W[g*8+j][h], j=0..7  (8 consecutive k at column h)
__global__ __launch_bounds__(256) void wt2_kernel(const float* __restrict__ Wq,
                                                  const float* __restrict__ Wk,
                                                  const float* __restrict__ Wv,
                                                  unsigned short* __restrict__ WT2) {
    int z = blockIdx.y;
    const float* W = (z == 0) ? Wq : (z == 1) ? Wk : Wv;
    unsigned short* o = WT2 + (size_t)z * H_ * E_;
    int gid = blockIdx.x * 256 + threadIdx.x;   // over (E_/8)*H_ = 16384 granules
    int g = gid >> 7, h = gid & 127;
    unsigned short t[8];
#pragma unroll
    for (int j = 0; j < 8; ++j)
        t[j] = f2bf(W[(size_t)(g * 8 + j) * H_ + h]);
    *(bf16x8*)&o[(size_t)(g * 128 + h) * 8] = *(const bf16x8*)t;
}

// ------ QKV projection: A in LDS (dbuf), B direct global->reg (L2-resident) --
// blockIdx.y = matrix (0=Q,1=K,2=V). V written TRANSPOSED [b][h][c].
__global__ __launch_bounds__(256) void proj_kernel(const float* __restrict__ x,
                                                   const unsigned short* __restrict__ WT2,
                                                   unsigned short* __restrict__ QKV) {
    __shared__ __align__(16) unsigned short As[2][64][64];    // 16 KB dbuf, XOR-swz

    const int tid = threadIdx.x;
    const int wid = tid >> 6, lane = tid & 63;
    const int lrow = lane & 15, lq = lane >> 4;
    const int wr = wid >> 1, wc = wid & 1;       // wave tile: rows wr*32, cols wc*64
    const int row0 = blockIdx.x * 64;
    const int w = blockIdx.y;
    const unsigned short* wt = WT2 + (size_t)w * H_ * E_;

    const int arow = tid >> 2;          // A staging row 0..63
    const int ag0 = (tid & 3) * 2;      // first of 2 granules per thread
    const float* xrow = x + (size_t)(row0 + arow) * E_ + ag0 * 8;

    f32x4 acc[2][4];
#pragma unroll
    for (int mi = 0; mi < 2; ++mi)
#pragma unroll
        for (int ni = 0; ni < 4; ++ni) acc[mi][ni] = (f32x4){0.f, 0.f, 0.f, 0.f};

    float4 a0, a1, a2, a3;
    bf16x8 breg[2][8];                  // static-indexed via full unroll

    auto A_LOAD = [&](int t) {
        const float* xs = xrow + t * 64;
        a0 = *(const float4*)xs;       a1 = *(const float4*)(xs + 4);
        a2 = *(const float4*)(xs + 8); a3 = *(const float4*)(xs + 12);
    };
    auto A_WRITE = [&](int buf) {
        unsigned short t0[8] = {f2bf(a0.x), f2bf(a0.y), f2bf(a0.z), f2bf(a0.w),
                                f2bf(a1.x), f2bf(a1.y), f2bf(a1.z), f2bf(a1.w)};
        unsigned short t1[8] = {f2bf(a2.x), f2bf(a2.y), f2bf(a2.z), f2bf(a2.w),
                                f2bf(a3.x), f2bf(a3.y), f2bf(a3.z), f2bf(a3.w)};
        *(bf16x8*)&As[buf][arow][(ag0 ^ (arow & 7)) * 8]       = *(const bf16x8*)t0;
        *(bf16x8*)&As[buf][arow][((ag0 + 1) ^ (arow & 7)) * 8] = *(const bf16x8*)t1;
    };

    // prologue
    A_LOAD(0);
#pragma unroll
    for (int i = 0; i < 8; ++i) {
        int g = (i >> 2) * 4 + lq;                         // ks*4+lq
        int rb = wc * 64 + (i & 3) * 16 + lrow;
        breg[0][i] = *(const bf16x8*)&wt[(size_t)(g * 128 + rb) * 8];
    }
    A_WRITE(0);

#pragma unroll
    for (int t = 0; t < 16; ++t) {
        const int cur = t & 1;
        __syncthreads();                 // As[cur] visible; prev reads done
        if (t < 15) {
            A_LOAD(t + 1);
#pragma unroll
            for (int i = 0; i < 8; ++i) {   // B(t+1) -> regs, 256B-coalesced L2 hits
                int g = (t + 1) * 8 + (i >> 2) * 4 + lq;
                int rb = wc * 64 + (i & 3) * 16 + lrow;
                breg[cur ^ 1][i] = *(const bf16x8*)&wt[(size_t)(g * 128 + rb) * 8];
            }
        }
        // compute tile t
#pragma unroll
        for (int ks = 0; ks < 2; ++ks) {
            const int g = ks * 4 + lq;
            bf16x8 af[2];
#pragma unroll
            for (int mi = 0; mi < 2; ++mi) {
                int ra = wr * 32 + mi * 16 + lrow;
                af[mi] = *(const bf16x8*)&As[cur][ra][(g ^ (ra & 7)) * 8];
            }
#pragma unroll
            for (int mi = 0; mi < 2; ++mi)
#pragma unroll
                for (int ni = 0; ni < 4; ++ni)
                    acc[mi][ni] = __builtin_amdgcn_mfma_f32_16x16x32_bf16(
                        af[mi], breg[cur][ks * 4 + ni], acc[mi][ni], 0, 0, 0);
        }
        if (t < 15) A_WRITE(cur ^ 1);    // waits A loads only; B still in flight
    }

    // epilogue: Q (scaled 1/32) and K row-major; V transposed [b][h][c]
    if (w < 2) {
        const float qs = (w == 0) ? 0.03125f : 1.0f;   // fold 1/sqrt(E) into Q
        unsigned short* outp = QKV + (size_t)w * M_ * H_;
#pragma unroll
        for (int mi = 0; mi < 2; ++mi) {
            int r0 = row0 + wr * 32 + mi * 16 + lq * 4;
#pragma unroll
            for (int ni = 0; ni < 4; ++ni) {
                int col = wc * 64 + ni * 16 + lrow;
#pragma unroll
                for (int r = 0; r < 4; ++r)
                    outp[(size_t)(r0 + r) * H_ + col] = f2bf(acc[mi][ni][r] * qs);
            }
        }
    } else {
        unsigned short* vt = QKV + (size_t)2 * M_ * H_;
        int b = row0 / C_;
        int cbase = row0 % C_;
#pragma unroll
        for (int mi = 0; mi < 2; ++mi) {
            int c0 = cbase + wr * 32 + mi * 16 + lq * 4;
#pragma unroll
            for (int ni = 0; ni < 4; ++ni) {
                int h = wc * 64 + ni * 16 + lrow;
                __align__(8) unsigned short p[4] = {f2bf(acc[mi][ni][0]), f2bf(acc[mi][ni][1]),
                                                    f2bf(acc[mi][ni][2]), f2bf(acc[mi][ni][3])};
                *(uint2*)&vt[((size_t)b * H_ + h) * C_ + c0] = *(const uint2*)p;
            }
        }
    }
}

// ---------------- split-KV flash attention chunks ---------------------------
// grid (144, B): blockIdx.x = chunk slot within batch, decoded to (j, c).
__global__ __launch_bounds__(256) void attn_kernel(const unsigned short* __restrict__ QKV,
                                                   unsigned short* __restrict__ PO,
                                                   float* __restrict__ ML,
                                                   float* __restrict__ out) {
    __shared__ __align__(16) unsigned short Ks[2][64][128];
    __shared__ __align__(16) unsigned short Vt[2][128][64];
    __shared__ __align__(16) unsigned short Ps[4][16][72];

    const unsigned short* Q  = QKV;
    const unsigned short* K  = QKV + (size_t)M_ * H_;
    const unsigned short* VT = QKV + (size_t)2 * M_ * H_;

    const int tid = threadIdx.x, wid = tid >> 6, lane = tid & 63;
    const int lrow = lane & 15, lq = lane >> 4, lk = lq * 8;
    const int rr = blockIdx.x;          // 0..143
    const int b = blockIdx.y;

    // decode rr -> (j, c): C(j) = j + 2q(q-1) + s*q, q=j>>2, s=j&3
    int j = 0;
#pragma unroll
    for (int jj = 1; jj < 32; ++jj) {
        int q = jj >> 2, s = jj & 3;
        if (jj + 2 * q * (q - 1) + s * q <= rr) j = jj;
    }
    const int qj = j >> 2, sj = j & 3;
    const int Cj = j + 2 * qj * (qj - 1) + sj * qj;
    const int c = rr - Cj;
    const int nch = qj + 1;
    const int t0 = c * 4;
    const int t1 = min(t0 + 4, j + 1);

    const int q0w = j * 64 + wid * 16;
    const unsigned short* Kb  = K  + (size_t)b * C_ * H_;
    const unsigned short* VTb = VT + (size_t)b * H_ * C_;
    const int qrow0 = q0w + lq * 4;

    const int krow = tid >> 4, kg = tid & 15;
    const int vrow = tid >> 3, vg = tid & 7;

    bf16x8 qf[4];
#pragma unroll
    for (int kf = 0; kf < 4; ++kf)
        qf[kf] = *(const bf16x8*)&Q[((size_t)b * C_ + q0w + lrow) * H_ + kf * 32 + lk];

    f32x4 o[8];
#pragma unroll
    for (int nf = 0; nf < 8; ++nf) o[nf] = (f32x4){0.f, 0.f, 0.f, 0.f};
    float m[4] = {-INFINITY, -INFINITY, -INFINITY, -INFINITY};
    float l[4] = {0.f, 0.f, 0.f, 0.f};

    auto STAGE = [&](int buf, int t) {
        const int kv0 = t * 64;
#pragma unroll
        for (int s = 0; s < 4; ++s) {
            int r = s * 16 + krow;
            GLOAD_LDS16(&Kb[(size_t)(kv0 + r) * H_ + ((kg ^ (r & 15)) * 8)],
                        (char*)&Ks[buf][0][0] + s * 4096 + tid * 16);
        }
#pragma unroll
        for (int s = 0; s < 4; ++s) {
            int h = s * 32 + vrow;
            GLOAD_LDS16(&VTb[(size_t)h * C_ + kv0 + ((vg ^ (h & 7)) * 8)],
                        (char*)&Vt[buf][0][0] + s * 4096 + tid * 16);
        }
    };

    STAGE(0, t0);

    for (int t = t0; t < t1; ++t) {
        const int cur = (t - t0) & 1;
        __syncthreads();
        if (t + 1 < t1) STAGE(cur ^ 1, t + 1);

        const int kv0 = t * 64;
        f32x4 s[4];
#pragma unroll
        for (int nf = 0; nf < 4; ++nf) {
            s[nf] = (f32x4){0.f, 0.f, 0.f, 0.f};
            const int rk = nf * 16 + lrow;
#pragma unroll
            for (int kf = 0; kf < 4; ++kf) {
                bf16x8 kb = *(const bf16x8*)&Ks[cur][rk][((kf * 4 + lq) ^ (rk & 15)) * 8];
                s[nf] = __builtin_amdgcn_mfma_f32_16x16x32_bf16(qf[kf], kb, s[nf], 0, 0, 0);
            }
        }
        bf16x8 vb[8][2];
#pragma unroll
        for (int nf = 0; nf < 8; ++nf) {
            const int h = nf * 16 + lrow;
#pragma unroll
            for (int kf2 = 0; kf2 < 2; ++kf2)
                vb[nf][kf2] = *(const bf16x8*)&Vt[cur][h][((kf2 * 4 + lq) ^ (h & 7)) * 8];
        }

        if (t == j) {
#pragma unroll
            for (int nf = 0; nf < 4; ++nf) {
                int key = kv0 + nf * 16 + lrow;
#pragma unroll
                for (int r = 0; r < 4; ++r)
                    if (key > qrow0 + r) s[nf][r] = -INFINITY;
            }
        }
        float mt[4] = {-INFINITY, -INFINITY, -INFINITY, -INFINITY};
#pragma unroll
        for (int nf = 0; nf < 4; ++nf)
#pragma unroll
            for (int r = 0; r < 4; ++r) mt[r] = fmaxf(mt[r], s[nf][r]);
#pragma unroll
        for (int r = 0; r < 4; ++r)
#pragma unroll
            for (int off = 1; off < 16; off <<= 1)
                mt[r] = fmaxf(mt[r], __shfl_xor(mt[r], off));

        float corr[4];
#pragma unroll
        for (int r = 0; r < 4; ++r) {
            float mn = fmaxf(m[r], mt[r]);
            corr[r] = __expf(m[r] - mn);
            m[r] = mn;
        }
        float ps[4] = {0.f, 0.f, 0.f, 0.f};
#pragma unroll
        for (int nf = 0; nf < 4; ++nf)
#pragma unroll
            for (int r = 0; r < 4; ++r) {
                float p = __expf(s[nf][r] - m[r]);
                ps[r] += p;
                Ps[wid][lq * 4 + r][nf * 16 + lrow] = f2bf(p);
            }
#pragma unroll
        for (int r = 0; r < 4; ++r) {
#pragma unroll
            for (int off = 1; off < 16; off <<= 1) ps[r] += __shfl_xor(ps[r], off);
            l[r] = l[r] * corr[r] + ps[r];
        }
#pragma unroll
        for (int nf = 0; nf < 8; ++nf)
#pragma unroll
            for (int r = 0; r < 4; ++r) o[nf][r] *= corr[r];

        bf16x8 pa[2];
#pragma unroll
        for (int kf2 = 0; kf2 < 2; ++kf2)
            pa[kf2] = *(const bf16x8*)&Ps[wid][lrow][kf2 * 32 + lk];
#pragma unroll
        for (int nf = 0; nf < 8; ++nf)
#pragma unroll
            for (int kf2 = 0; kf2 < 2; ++kf2)
                o[nf] = __builtin_amdgcn_mfma_f32_16x16x32_bf16(pa[kf2], vb[nf][kf2], o[nf], 0, 0, 0);
    }

    if (nch == 1) {       // j <= 3: single chunk, write normalized
#pragma unroll
        for (int nf = 0; nf < 8; ++nf) {
            int col = nf * 16 + lrow;
#pragma unroll
            for (int r = 0; r < 4; ++r)
                out[((size_t)b * C_ + qrow0 + r) * H_ + col] = o[nf][r] / l[r];
        }
    } else {              // partial: O (bf16, unnormalized) + m,l
        const int slot = b * SLOTS_B + rr;
        unsigned short* po = PO + (size_t)slot * 64 * 128;
        const int rl0 = wid * 16 + lq * 4;
#pragma unroll
        for (int nf = 0; nf < 8; ++nf) {
            int col = nf * 16 + lrow;
#pragma unroll
            for (int r = 0; r < 4; ++r)
                po[(size_t)(rl0 + r) * 128 + col] = f2bf(o[nf][r]);
        }
        if (lrow == 0) {
            float* ml = ML + (size_t)slot * 128;
#pragma unroll
            for (int r = 0; r < 4; ++r) {
                ml[rl0 + r] = m[r];
                ml[64 + rl0 + r] = l[r];
            }
        }
    }
}

// ---------------- combine partials for j >= 4 --------------------------------
__global__ __launch_bounds__(256) void combine_kernel(const unsigned short* __restrict__ PO,
                                                      const float* __restrict__ ML,
                                                      float* __restrict__ out) {
    const int j = blockIdx.x + 4;
    const int b = blockIdx.y;
    const int q = j >> 2, s = j & 3;
    const int Cj = j + 2 * q * (q - 1) + s * q;
    const int nch = q + 1;
    const int base = b * SLOTS_B + Cj;
    const int row = threadIdx.x >> 2;
    const int colg = (threadIdx.x & 3) * 32;

    float mstar = -INFINITY;
    for (int c = 0; c < nch; ++c)
        mstar = fmaxf(mstar, ML[(size_t)(base + c) * 128 + row]);

    float denom = 0.f;
    float acc[32];
#pragma unroll
    for (int i = 0; i < 32; ++i) acc[i] = 0.f;

    for (int c = 0; c < nch; ++c) {
        float mc = ML[(size_t)(base + c) * 128 + row];
        float lc = ML[(size_t)(base + c) * 128 + 64 + row];
        float w = __expf(mc - mstar);
        denom += w * lc;
        const unsigned short* p = PO + (size_t)(base + c) * 64 * 128 + (size_t)row * 128 + colg;
#pragma unroll
        for (int k = 0; k < 4; ++k) {
            bf16x8 v = *(const bf16x8*)&p[k * 8];
#pragma unroll
            for (int e = 0; e < 8; ++e)
                acc[k * 8 + e] += w * bf2f(((unsigned short*)&v)[e]);
        }
    }
    float inv = 1.f / denom;
    float* op = out + ((size_t)b * C_ + j * 64 + row) * H_ + colg;
#pragma unroll
    for (int k = 0; k < 8; ++k) {
        float4 st = {acc[k * 4] * inv, acc[k * 4 + 1] * inv, acc[k * 4 + 2] * inv, acc[k * 4 + 3] * inv};
        *(float4*)&op[k * 4] = st;
    }
}

extern "C" void kernel_launch(void* const* d_in, const int* in_sizes, int n_in,
                              void* d_out, int out_size, void* d_ws, size_t ws_size,
                              hipStream_t stream) {
    const float* x  = (const float*)d_in[0];
    const float* Wq = (const float*)d_in[1];
    const float* Wk = (const float*)d_in[2];
    const float* Wv = (const float*)d_in[3];
    float* out = (float*)d_out;

    // ws layout (~31.4 MB total):
    unsigned short* WT2 = (unsigned short*)d_ws;                       // 768 KB
    unsigned short* QKV = WT2 + (size_t)3 * H_ * E_;                   // 12 MB (Q, K, V^T)
    unsigned short* PO  = QKV + (size_t)3 * M_ * H_;                   // 18 MB partial O
    float*          ML  = (float*)(PO + (size_t)8 * SLOTS_B * 64 * 128); // 576 KB m,l

    wt2_kernel<<<dim3(E_ / 8 * H_ / 256, 3), 256, 0, stream>>>(Wq, Wk, Wv, WT2);
    proj_kernel<<<dim3(M_ / 64, 3), 256, 0, stream>>>(x, WT2, QKV);
    attn_kernel<<<dim3(SLOTS_B, B_), 256, 0, stream>>>(QKV, PO, ML, out);
    combine_kernel<<<dim3(28, B_), 256, 0, stream>>>(PO, ML, out);
}

// Round 8
// 83.960 us; speedup vs baseline: 1.0110x; 1.0110x over previous
//
#include <hip/hip_runtime.h>
#include <hip/hip_bf16.h>
#include <stdint.h>

#define B_ 8
#define C_ 2048
#define E_ 1024
#define H_ 128
#define M_ (B_*C_)      // 16384 rows total
#define SLOTS_B 144     // chunks per batch: sum_j ceil((j+1)/4), j<32

typedef __attribute__((ext_vector_type(8))) short bf16x8;
typedef __attribute__((ext_vector_type(4))) float f32x4;

__device__ __forceinline__ unsigned short f2bf(float f) {
    union { float f; unsigned int u; } v; v.f = f;
    unsigned int u = v.u;
    u += 0x7fff + ((u >> 16) & 1);   // RNE
    return (unsigned short)(u >> 16);
}
__device__ __forceinline__ float bf2f(unsigned short u) {
    union { unsigned int i; float f; } v; v.i = ((unsigned int)u) << 16; return v.f;
}

#define GLOAD_LDS16(g, l) \
    __builtin_amdgcn_global_load_lds((const __attribute__((address_space(1))) void*)(g), \
                                     (__attribute__((address_space(3))) void*)(l), 16, 0, 0)

// -------- W -> fragment-ordered bf16: WT2[w][g*128 + h] = 16B granule -------
// granule (g,h) holds W[g*8+j][h], j=0..7  (8 consecutive k at column h)
__global__ __launch_bounds__(256) void wt2_kernel(const float* __restrict__ Wq,
                                                  const float* __restrict__ Wk,
                                                  const float* __restrict__ Wv,
                                                  unsigned short* __restrict__ WT2) {
    int z = blockIdx.y;
    const float* W = (z == 0) ? Wq : (z == 1) ? Wk : Wv;
    unsigned short* o = WT2 + (size_t)z * H_ * E_;
    int gid = blockIdx.x * 256 + threadIdx.x;   // over (E_/8)*H_ = 16384 granules
    int g = gid >> 7, h = gid & 127;
    unsigned short t[8];
#pragma unroll
    for (int j = 0; j < 8; ++j)
        t[j] = f2bf(W[(size_t)(g * 8 + j) * H_ + h]);
    *(bf16x8*)&o[(size_t)(g * 128 + h) * 8] = *(const bf16x8*)t;
}

// ------ QKV projection: A in LDS (dbuf), B global->reg, fully static pipeline
// blockIdx.y = matrix (0=Q,1=K,2=V). V written TRANSPOSED [b][h][c].
#define MF(a, b, c) __builtin_amdgcn_mfma_f32_16x16x32_bf16((a), (b), (c), 0, 0, 0)

#define ALOAD(S, T) { const float* xs_ = xrow + (T) * 64; \
    a##S##_0 = *(const float4*)xs_;        a##S##_1 = *(const float4*)(xs_ + 4); \
    a##S##_2 = *(const float4*)(xs_ + 8);  a##S##_3 = *(const float4*)(xs_ + 12); }

#define AWRITE(S, BUF) { \
    unsigned short t0_[8] = {f2bf(a##S##_0.x), f2bf(a##S##_0.y), f2bf(a##S##_0.z), f2bf(a##S##_0.w), \
                             f2bf(a##S##_1.x), f2bf(a##S##_1.y), f2bf(a##S##_1.z), f2bf(a##S##_1.w)}; \
    unsigned short t1_[8] = {f2bf(a##S##_2.x), f2bf(a##S##_2.y), f2bf(a##S##_2.z), f2bf(a##S##_2.w), \
                             f2bf(a##S##_3.x), f2bf(a##S##_3.y), f2bf(a##S##_3.z), f2bf(a##S##_3.w)}; \
    *(bf16x8*)&As[BUF][arow][(ag0 ^ (arow & 7)) * 8]       = *(const bf16x8*)t0_; \
    *(bf16x8*)&As[BUF][arow][((ag0 + 1) ^ (arow & 7)) * 8] = *(const bf16x8*)t1_; }

#define BLOAD(S, T) { const unsigned short* wp_ = wbase + (size_t)(T) * 8192; \
    b##S##0 = *(const bf16x8*)(wp_);        b##S##1 = *(const bf16x8*)(wp_ + 128); \
    b##S##2 = *(const bf16x8*)(wp_ + 256);  b##S##3 = *(const bf16x8*)(wp_ + 384); \
    b##S##4 = *(const bf16x8*)(wp_ + 4096); b##S##5 = *(const bf16x8*)(wp_ + 4224); \
    b##S##6 = *(const bf16x8*)(wp_ + 4352); b##S##7 = *(const bf16x8*)(wp_ + 4480); }

#define COMPUTE(BUF, S) { \
    bf16x8 af00 = *(const bf16x8*)&As[BUF][ra0][(lq ^ (ra0 & 7)) * 8]; \
    bf16x8 af01 = *(const bf16x8*)&As[BUF][ra1][(lq ^ (ra1 & 7)) * 8]; \
    acc[0][0] = MF(af00, b##S##0, acc[0][0]);  acc[1][0] = MF(af01, b##S##0, acc[1][0]); \
    acc[0][1] = MF(af00, b##S##1, acc[0][1]);  acc[1][1] = MF(af01, b##S##1, acc[1][1]); \
    acc[0][2] = MF(af00, b##S##2, acc[0][2]);  acc[1][2] = MF(af01, b##S##2, acc[1][2]); \
    acc[0][3] = MF(af00, b##S##3, acc[0][3]);  acc[1][3] = MF(af01, b##S##3, acc[1][3]); \
    bf16x8 af10 = *(const bf16x8*)&As[BUF][ra0][((4 + lq) ^ (ra0 & 7)) * 8]; \
    bf16x8 af11 = *(const bf16x8*)&As[BUF][ra1][((4 + lq) ^ (ra1 & 7)) * 8]; \
    acc[0][0] = MF(af10, b##S##4, acc[0][0]);  acc[1][0] = MF(af11, b##S##4, acc[1][0]); \
    acc[0][1] = MF(af10, b##S##5, acc[0][1]);  acc[1][1] = MF(af11, b##S##5, acc[1][1]); \
    acc[0][2] = MF(af10, b##S##6, acc[0][2]);  acc[1][2] = MF(af11, b##S##6, acc[1][2]); \
    acc[0][3] = MF(af10, b##S##7, acc[0][3]);  acc[1][3] = MF(af11, b##S##7, acc[1][3]); }

// steady-state schedule (tile T regs live in set T&1; A 2-deep, B 2-deep):
#define EVEN_STEP(K) { \
    __syncthreads(); \
    AWRITE(B, 1);                                  /* tile K+1 -> buf1 */ \
    if ((K) + 3 <= 15) ALOAD(B, (K) + 3); \
    COMPUTE(0, A);                                 /* tile K */ \
    if ((K) + 2 <= 15) BLOAD(A, (K) + 2); }

#define ODD_STEP(K) { \
    __syncthreads(); \
    if ((K) + 1 <= 15) AWRITE(A, 0);               /* tile K+1 -> buf0 */ \
    if ((K) + 3 <= 15) ALOAD(A, (K) + 3); \
    COMPUTE(1, B);                                 /* tile K */ \
    if ((K) + 2 <= 15) BLOAD(B, (K) + 2); }

__global__ __launch_bounds__(256) void proj_kernel(const float* __restrict__ x,
                                                   const unsigned short* __restrict__ WT2,
                                                   unsigned short* __restrict__ QKV) {
    __shared__ __align__(16) unsigned short As[2][64][64];    // 16 KB dbuf, XOR-swz

    const int tid = threadIdx.x;
    const int wid = tid >> 6, lane = tid & 63;
    const int lrow = lane & 15, lq = lane >> 4;
    const int wr = wid >> 1, wc = wid & 1;       // wave tile: rows wr*32, cols wc*64
    const int row0 = blockIdx.x * 64;
    const int w = blockIdx.y;
    const unsigned short* wt = WT2 + (size_t)w * H_ * E_;

    const int arow = tid >> 2;          // A staging row 0..63
    const int ag0 = (tid & 3) * 2;      // first of 2 granules per thread
    const float* xrow = x + (size_t)(row0 + arow) * E_ + ag0 * 8;
    const int ra0 = wr * 32 + lrow, ra1 = wr * 32 + 16 + lrow;

    // B granule base for this lane; frag i at step T:
    //   offset = T*8192 + (i>>2)*4096 + (i&3)*128 shorts
    const unsigned short* wbase = wt + (size_t)(lq * 128 + wc * 64 + lrow) * 8;

    f32x4 acc[2][4];
#pragma unroll
    for (int mi = 0; mi < 2; ++mi)
#pragma unroll
        for (int ni = 0; ni < 4; ++ni) acc[mi][ni] = (f32x4){0.f, 0.f, 0.f, 0.f};

    float4 aA_0, aA_1, aA_2, aA_3, aB_0, aB_1, aB_2, aB_3;
    bf16x8 bA0, bA1, bA2, bA3, bA4, bA5, bA6, bA7;
    bf16x8 bB0, bB1, bB2, bB3, bB4, bB5, bB6, bB7;

    // prologue
    ALOAD(A, 0); BLOAD(A, 0);
    ALOAD(B, 1); BLOAD(B, 1);
    AWRITE(A, 0);           // tile 0 -> buf0 (waits only set-A loads)
    ALOAD(A, 2);            // tile 2 in flight

    EVEN_STEP(0)  ODD_STEP(1)  EVEN_STEP(2)  ODD_STEP(3)
    EVEN_STEP(4)  ODD_STEP(5)  EVEN_STEP(6)  ODD_STEP(7)
    EVEN_STEP(8)  ODD_STEP(9)  EVEN_STEP(10) ODD_STEP(11)
    EVEN_STEP(12) ODD_STEP(13) EVEN_STEP(14) ODD_STEP(15)

    // epilogue: Q (scaled 1/32) and K row-major; V transposed [b][h][c]
    if (w < 2) {
        const float qs = (w == 0) ? 0.03125f : 1.0f;   // fold 1/sqrt(E) into Q
        unsigned short* outp = QKV + (size_t)w * M_ * H_;
#pragma unroll
        for (int mi = 0; mi < 2; ++mi) {
            int r0 = row0 + wr * 32 + mi * 16 + lq * 4;
#pragma unroll
            for (int ni = 0; ni < 4; ++ni) {
                int col = wc * 64 + ni * 16 + lrow;
#pragma unroll
                for (int r = 0; r < 4; ++r)
                    outp[(size_t)(r0 + r) * H_ + col] = f2bf(acc[mi][ni][r] * qs);
            }
        }
    } else {
        unsigned short* vt = QKV + (size_t)2 * M_ * H_;
        int b = row0 / C_;
        int cbase = row0 % C_;
#pragma unroll
        for (int mi = 0; mi < 2; ++mi) {
            int c0 = cbase + wr * 32 + mi * 16 + lq * 4;
#pragma unroll
            for (int ni = 0; ni < 4; ++ni) {
                int h = wc * 64 + ni * 16 + lrow;
                __align__(8) unsigned short p[4] = {f2bf(acc[mi][ni][0]), f2bf(acc[mi][ni][1]),
                                                    f2bf(acc[mi][ni][2]), f2bf(acc[mi][ni][3])};
                *(uint2*)&vt[((size_t)b * H_ + h) * C_ + c0] = *(const uint2*)p;
            }
        }
    }
}

// ---------------- split-KV flash attention chunks ---------------------------
// grid (144, B): blockIdx.x = chunk slot within batch, decoded to (j, c).
__global__ __launch_bounds__(256) void attn_kernel(const unsigned short* __restrict__ QKV,
                                                   unsigned short* __restrict__ PO,
                                                   float* __restrict__ ML,
                                                   float* __restrict__ out) {
    __shared__ __align__(16) unsigned short Ks[2][64][128];
    __shared__ __align__(16) unsigned short Vt[2][128][64];
    __shared__ __align__(16) unsigned short Ps[4][16][72];

    const unsigned short* Q  = QKV;
    const unsigned short* K  = QKV + (size_t)M_ * H_;
    const unsigned short* VT = QKV + (size_t)2 * M_ * H_;

    const int tid = threadIdx.x, wid = tid >> 6, lane = tid & 63;
    const int lrow = lane & 15, lq = lane >> 4, lk = lq * 8;
    const int rr = blockIdx.x;          // 0..143
    const int b = blockIdx.y;

    // decode rr -> (j, c): C(j) = j + 2q(q-1) + s*q, q=j>>2, s=j&3
    int j = 0;
#pragma unroll
    for (int jj = 1; jj < 32; ++jj) {
        int q = jj >> 2, s = jj & 3;
        if (jj + 2 * q * (q - 1) + s * q <= rr) j = jj;
    }
    const int qj = j >> 2, sj = j & 3;
    const int Cj = j + 2 * qj * (qj - 1) + sj * qj;
    const int c = rr - Cj;
    const int nch = qj + 1;
    const int t0 = c * 4;
    const int t1 = min(t0 + 4, j + 1);

    const int q0w = j * 64 + wid * 16;
    const unsigned short* Kb  = K  + (size_t)b * C_ * H_;
    const unsigned short* VTb = VT + (size_t)b * H_ * C_;
    const int qrow0 = q0w + lq * 4;

    const int krow = tid >> 4, kg = tid & 15;
    const int vrow = tid >> 3, vg = tid & 7;

    bf16x8 qf[4];
#pragma unroll
    for (int kf = 0; kf < 4; ++kf)
        qf[kf] = *(const bf16x8*)&Q[((size_t)b * C_ + q0w + lrow) * H_ + kf * 32 + lk];

    f32x4 o[8];
#pragma unroll
    for (int nf = 0; nf < 8; ++nf) o[nf] = (f32x4){0.f, 0.f, 0.f, 0.f};
    float m[4] = {-INFINITY, -INFINITY, -INFINITY, -INFINITY};
    float l[4] = {0.f, 0.f, 0.f, 0.f};

    auto STAGE = [&](int buf, int t) {
        const int kv0 = t * 64;
#pragma unroll
        for (int s = 0; s < 4; ++s) {
            int r = s * 16 + krow;
            GLOAD_LDS16(&Kb[(size_t)(kv0 + r) * H_ + ((kg ^ (r & 15)) * 8)],
                        (char*)&Ks[buf][0][0] + s * 4096 + tid * 16);
        }
#pragma unroll
        for (int s = 0; s < 4; ++s) {
            int h = s * 32 + vrow;
            GLOAD_LDS16(&VTb[(size_t)h * C_ + kv0 + ((vg ^ (h & 7)) * 8)],
                        (char*)&Vt[buf][0][0] + s * 4096 + tid * 16);
        }
    };

    STAGE(0, t0);

    for (int t = t0; t < t1; ++t) {
        const int cur = (t - t0) & 1;
        __syncthreads();
        if (t + 1 < t1) STAGE(cur ^ 1, t + 1);

        const int kv0 = t * 64;
        f32x4 s[4];
#pragma unroll
        for (int nf = 0; nf < 4; ++nf) {
            s[nf] = (f32x4){0.f, 0.f, 0.f, 0.f};
            const int rk = nf * 16 + lrow;
#pragma unroll
            for (int kf = 0; kf < 4; ++kf) {
                bf16x8 kb = *(const bf16x8*)&Ks[cur][rk][((kf * 4 + lq) ^ (rk & 15)) * 8];
                s[nf] = __builtin_amdgcn_mfma_f32_16x16x32_bf16(qf[kf], kb, s[nf], 0, 0, 0);
            }
        }
        bf16x8 vb[8][2];
#pragma unroll
        for (int nf = 0; nf < 8; ++nf) {
            const int h = nf * 16 + lrow;
#pragma unroll
            for (int kf2 = 0; kf2 < 2; ++kf2)
                vb[nf][kf2] = *(const bf16x8*)&Vt[cur][h][((kf2 * 4 + lq) ^ (h & 7)) * 8];
        }

        if (t == j) {
#pragma unroll
            for (int nf = 0; nf < 4; ++nf) {
                int key = kv0 + nf * 16 + lrow;
#pragma unroll
                for (int r = 0; r < 4; ++r)
                    if (key > qrow0 + r) s[nf][r] = -INFINITY;
            }
        }
        float mt[4] = {-INFINITY, -INFINITY, -INFINITY, -INFINITY};
#pragma unroll
        for (int nf = 0; nf < 4; ++nf)
#pragma unroll
            for (int r = 0; r < 4; ++r) mt[r] = fmaxf(mt[r], s[nf][r]);
#pragma unroll
        for (int r = 0; r < 4; ++r)
#pragma unroll
            for (int off = 1; off < 16; off <<= 1)
                mt[r] = fmaxf(mt[r], __shfl_xor(mt[r], off));

        float corr[4];
#pragma unroll
        for (int r = 0; r < 4; ++r) {
            float mn = fmaxf(m[r], mt[r]);
            corr[r] = __expf(m[r] - mn);
            m[r] = mn;
        }
        float ps[4] = {0.f, 0.f, 0.f, 0.f};
#pragma unroll
        for (int nf = 0; nf < 4; ++nf)
#pragma unroll
            for (int r = 0; r < 4; ++r) {
                float p = __expf(s[nf][r] - m[r]);
                ps[r] += p;
                Ps[wid][lq * 4 + r][nf * 16 + lrow] = f2bf(p);
            }
#pragma unroll
        for (int r = 0; r < 4; ++r) {
#pragma unroll
            for (int off = 1; off < 16; off <<= 1) ps[r] += __shfl_xor(ps[r], off);
            l[r] = l[r] * corr[r] + ps[r];
        }
#pragma unroll
        for (int nf = 0; nf < 8; ++nf)
#pragma unroll
            for (int r = 0; r < 4; ++r) o[nf][r] *= corr[r];

        bf16x8 pa[2];
#pragma unroll
        for (int kf2 = 0; kf2 < 2; ++kf2)
            pa[kf2] = *(const bf16x8*)&Ps[wid][lrow][kf2 * 32 + lk];
#pragma unroll
        for (int nf = 0; nf < 8; ++nf)
#pragma unroll
            for (int kf2 = 0; kf2 < 2; ++kf2)
                o[nf] = __builtin_amdgcn_mfma_f32_16x16x32_bf16(pa[kf2], vb[nf][kf2], o[nf], 0, 0, 0);
    }

    if (nch == 1) {       // j <= 3: single chunk, write normalized
#pragma unroll
        for (int nf = 0; nf < 8; ++nf) {
            int col = nf * 16 + lrow;
#pragma unroll
            for (int r = 0; r < 4; ++r)
                out[((size_t)b * C_ + qrow0 + r) * H_ + col] = o[nf][r] / l[r];
        }
    } else {              // partial: O (bf16, unnormalized) + m,l
        const int slot = b * SLOTS_B + rr;
        unsigned short* po = PO + (size_t)slot * 64 * 128;
        const int rl0 = wid * 16 + lq * 4;
#pragma unroll
        for (int nf = 0; nf < 8; ++nf) {
            int col = nf * 16 + lrow;
#pragma unroll
            for (int r = 0; r < 4; ++r)
                po[(size_t)(rl0 + r) * 128 + col] = f2bf(o[nf][r]);
        }
        if (lrow == 0) {
            float* ml = ML + (size_t)slot * 128;
#pragma unroll
            for (int r = 0; r < 4; ++r) {
                ml[rl0 + r] = m[r];
                ml[64 + rl0 + r] = l[r];
            }
        }
    }
}

// ---------------- combine partials for j >= 4 --------------------------------
__global__ __launch_bounds__(256) void combine_kernel(const unsigned short* __restrict__ PO,
                                                      const float* __restrict__ ML,
                                                      float* __restrict__ out) {
    const int j = blockIdx.x + 4;
    const int b = blockIdx.y;
    const int q = j >> 2, s = j & 3;
    const int Cj = j + 2 * q * (q - 1) + s * q;
    const int nch = q + 1;
    const int base = b * SLOTS_B + Cj;
    const int row = threadIdx.x >> 2;
    const int colg = (threadIdx.x & 3) * 32;

    float mstar = -INFINITY;
    for (int c = 0; c < nch; ++c)
        mstar = fmaxf(mstar, ML[(size_t)(base + c) * 128 + row]);

    float denom = 0.f;
    float acc[32];
#pragma unroll
    for (int i = 0; i < 32; ++i) acc[i] = 0.f;

    for (int c = 0; c < nch; ++c) {
        float mc = ML[(size_t)(base + c) * 128 + row];
        float lc = ML[(size_t)(base + c) * 128 + 64 + row];
        float w = __expf(mc - mstar);
        denom += w * lc;
        const unsigned short* p = PO + (size_t)(base + c) * 64 * 128 + (size_t)row * 128 + colg;
#pragma unroll
        for (int k = 0; k < 4; ++k) {
            bf16x8 v = *(const bf16x8*)&p[k * 8];
#pragma unroll
            for (int e = 0; e < 8; ++e)
                acc[k * 8 + e] += w * bf2f(((unsigned short*)&v)[e]);
        }
    }
    float inv = 1.f / denom;
    float* op = out + ((size_t)b * C_ + j * 64 + row) * H_ + colg;
#pragma unroll
    for (int k = 0; k < 8; ++k) {
        float4 st = {acc[k * 4] * inv, acc[k * 4 + 1] * inv, acc[k * 4 + 2] * inv, acc[k * 4 + 3] * inv};
        *(float4*)&op[k * 4] = st;
    }
}

extern "C" void kernel_launch(void* const* d_in, const int* in_sizes, int n_in,
                              void* d_out, int out_size, void* d_ws, size_t ws_size,
                              hipStream_t stream) {
    const float* x  = (const float*)d_in[0];
    const float* Wq = (const float*)d_in[1];
    const float* Wk = (const float*)d_in[2];
    const float* Wv = (const float*)d_in[3];
    float* out = (float*)d_out;

    // ws layout (~31.4 MB total):
    unsigned short* WT2 = (unsigned short*)d_ws;                       // 768 KB
    unsigned short* QKV = WT2 + (size_t)3 * H_ * E_;                   // 12 MB (Q, K, V^T)
    unsigned short* PO  = QKV + (size_t)3 * M_ * H_;                   // 18 MB partial O
    float*          ML  = (float*)(PO + (size_t)8 * SLOTS_B * 64 * 128); // 576 KB m,l

    wt2_kernel<<<dim3(E_ / 8 * H_ / 256, 3), 256, 0, stream>>>(Wq, Wk, Wv, WT2);
    proj_kernel<<<dim3(M_ / 64, 3), 256, 0, stream>>>(x, WT2, QKV);
    attn_kernel<<<dim3(SLOTS_B, B_), 256, 0, stream>>>(QKV, PO, ML, out);
    combine_kernel<<<dim3(28, B_), 256, 0, stream>>>(PO, ML, out);
}

// Round 9
// 79.461 us; speedup vs baseline: 1.0683x; 1.0566x over previous
//
#include <hip/hip_runtime.h>
#include <hip/hip_bf16.h>
#include <stdint.h>

#define B_ 8
#define C_ 2048
#define E_ 1024
#define H_ 128
#define M_ (B_*C_)      // 16384 rows total
#define SLOTS_B 144     // chunks per batch: sum_j ceil((j+1)/4), j<32

typedef __attribute__((ext_vector_type(8))) short bf16x8;
typedef __attribute__((ext_vector_type(4))) float f32x4;

__device__ __forceinline__ unsigned short f2bf(float f) {
    union { float f; unsigned int u; } v; v.f = f;
    unsigned int u = v.u;
    u += 0x7fff + ((u >> 16) & 1);   // RNE
    return (unsigned short)(u >> 16);
}
__device__ __forceinline__ float bf2f(unsigned short u) {
    union { unsigned int i; float f; } v; v.i = ((unsigned int)u) << 16; return v.f;
}

#define GLOAD_LDS16(g, l) \
    __builtin_amdgcn_global_load_lds((const __attribute__((address_space(1))) void*)(g), \
                                     (__attribute__((address_space(3))) void*)(l), 16, 0, 0)

// -------- W -> fragment-ordered bf16: WT2[w][g*128 + h] = 16B granule -------
// granule (g,h) holds W[g*8+j][h], j=0..7  (8 consecutive k at column h)
__global__ __launch_bounds__(256) void wt2_kernel(const float* __restrict__ Wq,
                                                  const float* __restrict__ Wk,
                                                  const float* __restrict__ Wv,
                                                  unsigned short* __restrict__ WT2) {
    int z = blockIdx.y;
    const float* W = (z == 0) ? Wq : (z == 1) ? Wk : Wv;
    unsigned short* o = WT2 + (size_t)z * H_ * E_;
    int gid = blockIdx.x * 256 + threadIdx.x;   // over (E_/8)*H_ = 16384 granules
    int g = gid >> 7, h = gid & 127;
    unsigned short t[8];
#pragma unroll
    for (int j = 0; j < 8; ++j)
        t[j] = f2bf(W[(size_t)(g * 8 + j) * H_ + h]);
    *(bf16x8*)&o[(size_t)(g * 128 + h) * 8] = *(const bf16x8*)t;
}

// ------ fused QKV projection: BM=32, x read ONCE, B direct global->reg ------
// grid 512 (2 blocks/CU). Per block: 32 rows x 128 cols x 3 matrices.
#define MF(a, b, c) __builtin_amdgcn_mfma_f32_16x16x32_bf16((a), (b), (c), 0, 0, 0)

#define ALOAD(S, T) { const float* xs_ = xrow + (T) * 64; \
    a##S##_0 = *(const float4*)xs_;  a##S##_1 = *(const float4*)(xs_ + 4); }

#define AWRITE(S, BUF) { \
    unsigned short t_[8] = {f2bf(a##S##_0.x), f2bf(a##S##_0.y), f2bf(a##S##_0.z), f2bf(a##S##_0.w), \
                            f2bf(a##S##_1.x), f2bf(a##S##_1.y), f2bf(a##S##_1.z), f2bf(a##S##_1.w)}; \
    *(bf16x8*)&As[BUF][arow][(ag ^ (arow & 7)) * 8] = *(const bf16x8*)t_; }

// B single-buffered: loads issued at step start, intra-step liveness only.
#define COMPUTE(BUF, T) { \
    bf16x8 bw[3][2][2]; \
    _Pragma("unroll") for (int w_ = 0; w_ < 3; ++w_) \
    _Pragma("unroll") for (int ks_ = 0; ks_ < 2; ++ks_) \
    _Pragma("unroll") for (int ni_ = 0; ni_ < 2; ++ni_) \
        bw[w_][ni_][ks_] = *(const bf16x8*)&WT2[(size_t)w_ * H_ * E_ + \
            (size_t)(((T) * 8 + ks_ * 4 + lq) * 128 + wcol + ni_ * 16 + lrow) * 8]; \
    bf16x8 af[2][2]; \
    _Pragma("unroll") for (int mi_ = 0; mi_ < 2; ++mi_) \
    _Pragma("unroll") for (int ks_ = 0; ks_ < 2; ++ks_) { \
        int ra_ = mi_ * 16 + lrow; \
        af[mi_][ks_] = *(const bf16x8*)&As[BUF][ra_][((ks_ * 4 + lq) ^ (ra_ & 7)) * 8]; \
    } \
    _Pragma("unroll") for (int ks_ = 0; ks_ < 2; ++ks_) \
    _Pragma("unroll") for (int w_ = 0; w_ < 3; ++w_) \
    _Pragma("unroll") for (int ni_ = 0; ni_ < 2; ++ni_) \
    _Pragma("unroll") for (int mi_ = 0; mi_ < 2; ++mi_) \
        acc[w_][mi_][ni_] = MF(af[mi_][ks_], bw[w_][ni_][ks_], acc[w_][mi_][ni_]); }

#define EVEN_STEP(K) { \
    __syncthreads(); \
    if ((K) + 1 <= 15) AWRITE(B, 1);               /* tile K+1 -> buf1 */ \
    if ((K) + 2 <= 15) ALOAD(A, (K) + 2); \
    COMPUTE(0, K); }

#define ODD_STEP(K) { \
    __syncthreads(); \
    if ((K) + 1 <= 15) AWRITE(A, 0);               /* tile K+1 -> buf0 */ \
    if ((K) + 2 <= 15) ALOAD(B, (K) + 2); \
    COMPUTE(1, K); }

__global__ __launch_bounds__(256) void proj_kernel(const float* __restrict__ x,
                                                   const unsigned short* __restrict__ WT2,
                                                   unsigned short* __restrict__ QKV) {
    __shared__ __align__(16) unsigned short As[2][32][64];    // 8 KB dbuf, XOR-swz

    const int tid = threadIdx.x;
    const int wid = tid >> 6, lane = tid & 63;
    const int lrow = lane & 15, lq = lane >> 4;
    const int wcol = wid * 32;          // wave's 32-col slice of H=128
    const int row0 = blockIdx.x * 32;

    const int arow = tid >> 3;          // A staging row 0..31
    const int ag = tid & 7;             // granule 0..7
    const float* xrow = x + (size_t)(row0 + arow) * E_ + ag * 8;

    f32x4 acc[3][2][2];
#pragma unroll
    for (int w = 0; w < 3; ++w)
#pragma unroll
        for (int mi = 0; mi < 2; ++mi)
#pragma unroll
            for (int ni = 0; ni < 2; ++ni) acc[w][mi][ni] = (f32x4){0.f, 0.f, 0.f, 0.f};

    float4 aA_0, aA_1, aB_0, aB_1;

    // prologue: tile0 -> buf0; tile1 loads in flight
    ALOAD(A, 0);
    AWRITE(A, 0);
    ALOAD(B, 1);

    EVEN_STEP(0)  ODD_STEP(1)  EVEN_STEP(2)  ODD_STEP(3)
    EVEN_STEP(4)  ODD_STEP(5)  EVEN_STEP(6)  ODD_STEP(7)
    EVEN_STEP(8)  ODD_STEP(9)  EVEN_STEP(10) ODD_STEP(11)
    EVEN_STEP(12) ODD_STEP(13) EVEN_STEP(14) ODD_STEP(15)

    // epilogue: Q (scaled 1/32), K row-major; V transposed [b][h][c]
#pragma unroll
    for (int w = 0; w < 2; ++w) {
        const float qs = (w == 0) ? 0.03125f : 1.0f;   // fold 1/sqrt(E) into Q
        unsigned short* outp = QKV + (size_t)w * M_ * H_;
#pragma unroll
        for (int mi = 0; mi < 2; ++mi) {
            int r0 = row0 + mi * 16 + lq * 4;
#pragma unroll
            for (int ni = 0; ni < 2; ++ni) {
                int col = wcol + ni * 16 + lrow;
#pragma unroll
                for (int r = 0; r < 4; ++r)
                    outp[(size_t)(r0 + r) * H_ + col] = f2bf(acc[w][mi][ni][r] * qs);
            }
        }
    }
    {
        unsigned short* vt = QKV + (size_t)2 * M_ * H_;
        int b = row0 / C_;
        int cbase = row0 % C_;
#pragma unroll
        for (int mi = 0; mi < 2; ++mi) {
            int c0 = cbase + mi * 16 + lq * 4;
#pragma unroll
            for (int ni = 0; ni < 2; ++ni) {
                int h = wcol + ni * 16 + lrow;
                __align__(8) unsigned short p[4] = {f2bf(acc[2][mi][ni][0]), f2bf(acc[2][mi][ni][1]),
                                                    f2bf(acc[2][mi][ni][2]), f2bf(acc[2][mi][ni][3])};
                *(uint2*)&vt[((size_t)b * H_ + h) * C_ + c0] = *(const uint2*)p;
            }
        }
    }
}

// ---------------- split-KV flash attention chunks ---------------------------
// grid (144, B): blockIdx.x = chunk slot within batch, decoded to (j, c).
__global__ __launch_bounds__(256) void attn_kernel(const unsigned short* __restrict__ QKV,
                                                   unsigned short* __restrict__ PO,
                                                   float* __restrict__ ML,
                                                   float* __restrict__ out) {
    __shared__ __align__(16) unsigned short Ks[2][64][128];
    __shared__ __align__(16) unsigned short Vt[2][128][64];
    __shared__ __align__(16) unsigned short Ps[4][16][72];

    const unsigned short* Q  = QKV;
    const unsigned short* K  = QKV + (size_t)M_ * H_;
    const unsigned short* VT = QKV + (size_t)2 * M_ * H_;

    const int tid = threadIdx.x, wid = tid >> 6, lane = tid & 63;
    const int lrow = lane & 15, lq = lane >> 4, lk = lq * 8;
    const int rr = blockIdx.x;          // 0..143
    const int b = blockIdx.y;

    // decode rr -> (j, c): C(j) = j + 2q(q-1) + s*q, q=j>>2, s=j&3
    int j = 0;
#pragma unroll
    for (int jj = 1; jj < 32; ++jj) {
        int q = jj >> 2, s = jj & 3;
        if (jj + 2 * q * (q - 1) + s * q <= rr) j = jj;
    }
    const int qj = j >> 2, sj = j & 3;
    const int Cj = j + 2 * qj * (qj - 1) + sj * qj;
    const int c = rr - Cj;
    const int nch = qj + 1;
    const int t0 = c * 4;
    const int t1 = min(t0 + 4, j + 1);

    const int q0w = j * 64 + wid * 16;
    const unsigned short* Kb  = K  + (size_t)b * C_ * H_;
    const unsigned short* VTb = VT + (size_t)b * H_ * C_;
    const int qrow0 = q0w + lq * 4;

    const int krow = tid >> 4, kg = tid & 15;
    const int vrow = tid >> 3, vg = tid & 7;

    bf16x8 qf[4];
#pragma unroll
    for (int kf = 0; kf < 4; ++kf)
        qf[kf] = *(const bf16x8*)&Q[((size_t)b * C_ + q0w + lrow) * H_ + kf * 32 + lk];

    f32x4 o[8];
#pragma unroll
    for (int nf = 0; nf < 8; ++nf) o[nf] = (f32x4){0.f, 0.f, 0.f, 0.f};
    float m[4] = {-INFINITY, -INFINITY, -INFINITY, -INFINITY};
    float l[4] = {0.f, 0.f, 0.f, 0.f};

    auto STAGE = [&](int buf, int t) {
        const int kv0 = t * 64;
#pragma unroll
        for (int s = 0; s < 4; ++s) {
            int r = s * 16 + krow;
            GLOAD_LDS16(&Kb[(size_t)(kv0 + r) * H_ + ((kg ^ (r & 15)) * 8)],
                        (char*)&Ks[buf][0][0] + s * 4096 + tid * 16);
        }
#pragma unroll
        for (int s = 0; s < 4; ++s) {
            int h = s * 32 + vrow;
            GLOAD_LDS16(&VTb[(size_t)h * C_ + kv0 + ((vg ^ (h & 7)) * 8)],
                        (char*)&Vt[buf][0][0] + s * 4096 + tid * 16);
        }
    };

    STAGE(0, t0);

    for (int t = t0; t < t1; ++t) {
        const int cur = (t - t0) & 1;
        __syncthreads();
        if (t + 1 < t1) STAGE(cur ^ 1, t + 1);

        const int kv0 = t * 64;
        f32x4 s[4];
#pragma unroll
        for (int nf = 0; nf < 4; ++nf) {
            s[nf] = (f32x4){0.f, 0.f, 0.f, 0.f};
            const int rk = nf * 16 + lrow;
#pragma unroll
            for (int kf = 0; kf < 4; ++kf) {
                bf16x8 kb = *(const bf16x8*)&Ks[cur][rk][((kf * 4 + lq) ^ (rk & 15)) * 8];
                s[nf] = __builtin_amdgcn_mfma_f32_16x16x32_bf16(qf[kf], kb, s[nf], 0, 0, 0);
            }
        }
        bf16x8 vb[8][2];
#pragma unroll
        for (int nf = 0; nf < 8; ++nf) {
            const int h = nf * 16 + lrow;
#pragma unroll
            for (int kf2 = 0; kf2 < 2; ++kf2)
                vb[nf][kf2] = *(const bf16x8*)&Vt[cur][h][((kf2 * 4 + lq) ^ (h & 7)) * 8];
        }

        if (t == j) {
#pragma unroll
            for (int nf = 0; nf < 4; ++nf) {
                int key = kv0 + nf * 16 + lrow;
#pragma unroll
                for (int r = 0; r < 4; ++r)
                    if (key > qrow0 + r) s[nf][r] = -INFINITY;
            }
        }
        float mt[4] = {-INFINITY, -INFINITY, -INFINITY, -INFINITY};
#pragma unroll
        for (int nf = 0; nf < 4; ++nf)
#pragma unroll
            for (int r = 0; r < 4; ++r) mt[r] = fmaxf(mt[r], s[nf][r]);
#pragma unroll
        for (int r = 0; r < 4; ++r)
#pragma unroll
            for (int off = 1; off < 16; off <<= 1)
                mt[r] = fmaxf(mt[r], __shfl_xor(mt[r], off));

        float corr[4];
#pragma unroll
        for (int r = 0; r < 4; ++r) {
            float mn = fmaxf(m[r], mt[r]);
            corr[r] = __expf(m[r] - mn);
            m[r] = mn;
        }
        float ps[4] = {0.f, 0.f, 0.f, 0.f};
#pragma unroll
        for (int nf = 0; nf < 4; ++nf)
#pragma unroll
            for (int r = 0; r < 4; ++r) {
                float p = __expf(s[nf][r] - m[r]);
                ps[r] += p;
                Ps[wid][lq * 4 + r][nf * 16 + lrow] = f2bf(p);
            }
#pragma unroll
        for (int r = 0; r < 4; ++r) {
#pragma unroll
            for (int off = 1; off < 16; off <<= 1) ps[r] += __shfl_xor(ps[r], off);
            l[r] = l[r] * corr[r] + ps[r];
        }
#pragma unroll
        for (int nf = 0; nf < 8; ++nf)
#pragma unroll
            for (int r = 0; r < 4; ++r) o[nf][r] *= corr[r];

        bf16x8 pa[2];
#pragma unroll
        for (int kf2 = 0; kf2 < 2; ++kf2)
            pa[kf2] = *(const bf16x8*)&Ps[wid][lrow][kf2 * 32 + lk];
#pragma unroll
        for (int nf = 0; nf < 8; ++nf)
#pragma unroll
            for (int kf2 = 0; kf2 < 2; ++kf2)
                o[nf] = __builtin_amdgcn_mfma_f32_16x16x32_bf16(pa[kf2], vb[nf][kf2], o[nf], 0, 0, 0);
    }

    if (nch == 1) {       // j <= 3: single chunk, write normalized
#pragma unroll
        for (int nf = 0; nf < 8; ++nf) {
            int col = nf * 16 + lrow;
#pragma unroll
            for (int r = 0; r < 4; ++r)
                out[((size_t)b * C_ + qrow0 + r) * H_ + col] = o[nf][r] / l[r];
        }
    } else {              // partial: O (bf16, unnormalized) + m,l
        const int slot = b * SLOTS_B + rr;
        unsigned short* po = PO + (size_t)slot * 64 * 128;
        const int rl0 = wid * 16 + lq * 4;
#pragma unroll
        for (int nf = 0; nf < 8; ++nf) {
            int col = nf * 16 + lrow;
#pragma unroll
            for (int r = 0; r < 4; ++r)
                po[(size_t)(rl0 + r) * 128 + col] = f2bf(o[nf][r]);
        }
        if (lrow == 0) {
            float* ml = ML + (size_t)slot * 128;
#pragma unroll
            for (int r = 0; r < 4; ++r) {
                ml[rl0 + r] = m[r];
                ml[64 + rl0 + r] = l[r];
            }
        }
    }
}

// ---------------- combine partials for j >= 4 --------------------------------
__global__ __launch_bounds__(256) void combine_kernel(const unsigned short* __restrict__ PO,
                                                      const float* __restrict__ ML,
                                                      float* __restrict__ out) {
    const int j = blockIdx.x + 4;
    const int b = blockIdx.y;
    const int q = j >> 2, s = j & 3;
    const int Cj = j + 2 * q * (q - 1) + s * q;
    const int nch = q + 1;
    const int base = b * SLOTS_B + Cj;
    const int row = threadIdx.x >> 2;
    const int colg = (threadIdx.x & 3) * 32;

    float mstar = -INFINITY;
    for (int c = 0; c < nch; ++c)
        mstar = fmaxf(mstar, ML[(size_t)(base + c) * 128 + row]);

    float denom = 0.f;
    float acc[32];
#pragma unroll
    for (int i = 0; i < 32; ++i) acc[i] = 0.f;

    for (int c = 0; c < nch; ++c) {
        float mc = ML[(size_t)(base + c) * 128 + row];
        float lc = ML[(size_t)(base + c) * 128 + 64 + row];
        float w = __expf(mc - mstar);
        denom += w * lc;
        const unsigned short* p = PO + (size_t)(base + c) * 64 * 128 + (size_t)row * 128 + colg;
#pragma unroll
        for (int k = 0; k < 4; ++k) {
            bf16x8 v = *(const bf16x8*)&p[k * 8];
#pragma unroll
            for (int e = 0; e < 8; ++e)
                acc[k * 8 + e] += w * bf2f(((unsigned short*)&v)[e]);
        }
    }
    float inv = 1.f / denom;
    float* op = out + ((size_t)b * C_ + j * 64 + row) * H_ + colg;
#pragma unroll
    for (int k = 0; k < 8; ++k) {
        float4 st = {acc[k * 4] * inv, acc[k * 4 + 1] * inv, acc[k * 4 + 2] * inv, acc[k * 4 + 3] * inv};
        *(float4*)&op[k * 4] = st;
    }
}

extern "C" void kernel_launch(void* const* d_in, const int* in_sizes, int n_in,
                              void* d_out, int out_size, void* d_ws, size_t ws_size,
                              hipStream_t stream) {
    const float* x  = (const float*)d_in[0];
    const float* Wq = (const float*)d_in[1];
    const float* Wk = (const float*)d_in[2];
    const float* Wv = (const float*)d_in[3];
    float* out = (float*)d_out;

    // ws layout (~31.4 MB total):
    unsigned short* WT2 = (unsigned short*)d_ws;                       // 768 KB
    unsigned short* QKV = WT2 + (size_t)3 * H_ * E_;                   // 12 MB (Q, K, V^T)
    unsigned short* PO  = QKV + (size_t)3 * M_ * H_;                   // 18 MB partial O
    float*          ML  = (float*)(PO + (size_t)8 * SLOTS_B * 64 * 128); // 576 KB m,l

    wt2_kernel<<<dim3(E_ / 8 * H_ / 256, 3), 256, 0, stream>>>(Wq, Wk, Wv, WT2);
    proj_kernel<<<dim3(M_ / 32), 256, 0, stream>>>(x, WT2, QKV);
    attn_kernel<<<dim3(SLOTS_B, B_), 256, 0, stream>>>(QKV, PO, ML, out);
    combine_kernel<<<dim3(28, B_), 256, 0, stream>>>(PO, ML, out);
}

// Round 10
// 76.270 us; speedup vs baseline: 1.1130x; 1.0418x over previous
//
#include <hip/hip_runtime.h>
#include <hip/hip_bf16.h>
#include <stdint.h>

#define B_ 8
#define C_ 2048
#define E_ 1024
#define H_ 128
#define M_ (B_*C_)      // 16384 rows total
#define SLOTS_B 144     // chunks per batch: sum_j ceil((j+1)/4), j<32

typedef __attribute__((ext_vector_type(8))) short bf16x8;
typedef __attribute__((ext_vector_type(4))) float f32x4;

__device__ __forceinline__ unsigned short f2bf(float f) {
    union { float f; unsigned int u; } v; v.f = f;
    unsigned int u = v.u;
    u += 0x7fff + ((u >> 16) & 1);   // RNE
    return (unsigned short)(u >> 16);
}
__device__ __forceinline__ float bf2f(unsigned short u) {
    union { unsigned int i; float f; } v; v.i = ((unsigned int)u) << 16; return v.f;
}

#define GLOAD_LDS16(g, l) \
    __builtin_amdgcn_global_load_lds((const __attribute__((address_space(1))) void*)(g), \
                                     (__attribute__((address_space(3))) void*)(l), 16, 0, 0)

// -------- W -> fragment-ordered bf16: WT2[w][g*128 + h] = 16B granule -------
__global__ __launch_bounds__(256) void wt2_kernel(const float* __restrict__ Wq,
                                                  const float* __restrict__ Wk,
                                                  const float* __restrict__ Wv,
                                                  unsigned short* __restrict__ WT2) {
    int z = blockIdx.y;
    const float* W = (z == 0) ? Wq : (z == 1) ? Wk : Wv;
    unsigned short* o = WT2 + (size_t)z * H_ * E_;
    int gid = blockIdx.x * 256 + threadIdx.x;   // over (E_/8)*H_ = 16384 granules
    int g = gid >> 7, h = gid & 127;
    unsigned short t[8];
#pragma unroll
    for (int j = 0; j < 8; ++j)
        t[j] = f2bf(W[(size_t)(g * 8 + j) * H_ + h]);
    *(bf16x8*)&o[(size_t)(g * 128 + h) * 8] = *(const bf16x8*)t;
}

// ------ fused QKV projection: BM=32, x once; B loads 1-step-ahead in regs ----
#define MF(a, b, c) __builtin_amdgcn_mfma_f32_16x16x32_bf16((a), (b), (c), 0, 0, 0)

#define ALOAD(S, T) { const float* xs_ = xrow + (T) * 64; \
    a##S##_0 = *(const float4*)xs_;  a##S##_1 = *(const float4*)(xs_ + 4); }

#define AWRITE(S, BUF) { \
    unsigned short t_[8] = {f2bf(a##S##_0.x), f2bf(a##S##_0.y), f2bf(a##S##_0.z), f2bf(a##S##_0.w), \
                            f2bf(a##S##_1.x), f2bf(a##S##_1.y), f2bf(a##S##_1.z), f2bf(a##S##_1.w)}; \
    *(bf16x8*)&As[BUF][arow][(ag ^ (arow & 7)) * 8] = *(const bf16x8*)t_; }

// 12 named B granules per set: index = w*4 + ks*2 + ni
// offset (shorts) = w*131072 + T*8192 + ks*4096 + ni*128
#define BLOAD(S, T) { const unsigned short* wp_ = wbase + (size_t)(T) * 8192; \
    b##S##0  = *(const bf16x8*)(wp_);            b##S##1  = *(const bf16x8*)(wp_ + 128); \
    b##S##2  = *(const bf16x8*)(wp_ + 4096);     b##S##3  = *(const bf16x8*)(wp_ + 4224); \
    b##S##4  = *(const bf16x8*)(wp_ + 131072);   b##S##5  = *(const bf16x8*)(wp_ + 131200); \
    b##S##6  = *(const bf16x8*)(wp_ + 135168);   b##S##7  = *(const bf16x8*)(wp_ + 135296); \
    b##S##8  = *(const bf16x8*)(wp_ + 262144);   b##S##9  = *(const bf16x8*)(wp_ + 262272); \
    b##S##10 = *(const bf16x8*)(wp_ + 266240);   b##S##11 = *(const bf16x8*)(wp_ + 266368); }

#define COMPUTE(BUF, S) { \
    bf16x8 af00 = *(const bf16x8*)&As[BUF][ra0][(lq ^ (ra0 & 7)) * 8]; \
    bf16x8 af10 = *(const bf16x8*)&As[BUF][ra1][(lq ^ (ra1 & 7)) * 8]; \
    acc[0][0][0] = MF(af00, b##S##0, acc[0][0][0]);  acc[0][1][0] = MF(af10, b##S##0, acc[0][1][0]); \
    acc[0][0][1] = MF(af00, b##S##1, acc[0][0][1]);  acc[0][1][1] = MF(af10, b##S##1, acc[0][1][1]); \
    acc[1][0][0] = MF(af00, b##S##4, acc[1][0][0]);  acc[1][1][0] = MF(af10, b##S##4, acc[1][1][0]); \
    acc[1][0][1] = MF(af00, b##S##5, acc[1][0][1]);  acc[1][1][1] = MF(af10, b##S##5, acc[1][1][1]); \
    acc[2][0][0] = MF(af00, b##S##8, acc[2][0][0]);  acc[2][1][0] = MF(af10, b##S##8, acc[2][1][0]); \
    acc[2][0][1] = MF(af00, b##S##9, acc[2][0][1]);  acc[2][1][1] = MF(af10, b##S##9, acc[2][1][1]); \
    bf16x8 af01 = *(const bf16x8*)&As[BUF][ra0][((4 + lq) ^ (ra0 & 7)) * 8]; \
    bf16x8 af11 = *(const bf16x8*)&As[BUF][ra1][((4 + lq) ^ (ra1 & 7)) * 8]; \
    acc[0][0][0] = MF(af01, b##S##2, acc[0][0][0]);  acc[0][1][0] = MF(af11, b##S##2, acc[0][1][0]); \
    acc[0][0][1] = MF(af01, b##S##3, acc[0][0][1]);  acc[0][1][1] = MF(af11, b##S##3, acc[0][1][1]); \
    acc[1][0][0] = MF(af01, b##S##6, acc[1][0][0]);  acc[1][1][0] = MF(af11, b##S##6, acc[1][1][0]); \
    acc[1][0][1] = MF(af01, b##S##7, acc[1][0][1]);  acc[1][1][1] = MF(af11, b##S##7, acc[1][1][1]); \
    acc[2][0][0] = MF(af01, b##S##10, acc[2][0][0]); acc[2][1][0] = MF(af11, b##S##10, acc[2][1][0]); \
    acc[2][0][1] = MF(af01, b##S##11, acc[2][0][1]); acc[2][1][1] = MF(af11, b##S##11, acc[2][1][1]); }

// step K: barrier -> issue (A,B)(K+1) -> compute K -> AWRITE(K+1)
#define STEP_E(K) { __syncthreads(); \
    if ((K) < 15) { ALOAD(O, (K)+1); BLOAD(O, (K)+1); } \
    COMPUTE((K)&1, E); \
    if ((K) < 15) AWRITE(O, ((K)+1)&1); }

#define STEP_O(K) { __syncthreads(); \
    if ((K) < 15) { ALOAD(E, (K)+1); BLOAD(E, (K)+1); } \
    COMPUTE((K)&1, O); \
    if ((K) < 15) AWRITE(E, ((K)+1)&1); }

__global__ __launch_bounds__(256) void proj_kernel(const float* __restrict__ x,
                                                   const unsigned short* __restrict__ WT2,
                                                   unsigned short* __restrict__ QKV) {
    __shared__ __align__(16) unsigned short As[2][32][64];    // 8 KB dbuf, XOR-swz

    const int tid = threadIdx.x;
    const int wid = tid >> 6, lane = tid & 63;
    const int lrow = lane & 15, lq = lane >> 4;
    const int wcol = wid * 32;          // wave's 32-col slice of H=128
    const int row0 = blockIdx.x * 32;

    const int arow = tid >> 3;          // A staging row 0..31
    const int ag = tid & 7;             // granule 0..7
    const float* xrow = x + (size_t)(row0 + arow) * E_ + ag * 8;
    const int ra0 = lrow, ra1 = 16 + lrow;
    const unsigned short* wbase = WT2 + (size_t)(lq * 128 + wcol + lrow) * 8;

    f32x4 acc[3][2][2];
#pragma unroll
    for (int w = 0; w < 3; ++w)
#pragma unroll
        for (int mi = 0; mi < 2; ++mi)
#pragma unroll
            for (int ni = 0; ni < 2; ++ni) acc[w][mi][ni] = (f32x4){0.f, 0.f, 0.f, 0.f};

    float4 aE_0, aE_1, aO_0, aO_1;
    bf16x8 bE0, bE1, bE2, bE3, bE4, bE5, bE6, bE7, bE8, bE9, bE10, bE11;
    bf16x8 bO0, bO1, bO2, bO3, bO4, bO5, bO6, bO7, bO8, bO9, bO10, bO11;

    // prologue: tile 0 staged (set E, buf0)
    ALOAD(E, 0); BLOAD(E, 0);
    AWRITE(E, 0);

    STEP_E(0)  STEP_O(1)  STEP_E(2)  STEP_O(3)
    STEP_E(4)  STEP_O(5)  STEP_E(6)  STEP_O(7)
    STEP_E(8)  STEP_O(9)  STEP_E(10) STEP_O(11)
    STEP_E(12) STEP_O(13) STEP_E(14) STEP_O(15)

    // epilogue: Q (scaled 1/32), K row-major; V transposed [b][h][c]
#pragma unroll
    for (int w = 0; w < 2; ++w) {
        const float qs = (w == 0) ? 0.03125f : 1.0f;   // fold 1/sqrt(E) into Q
        unsigned short* outp = QKV + (size_t)w * M_ * H_;
#pragma unroll
        for (int mi = 0; mi < 2; ++mi) {
            int r0 = row0 + mi * 16 + lq * 4;
#pragma unroll
            for (int ni = 0; ni < 2; ++ni) {
                int col = wcol + ni * 16 + lrow;
#pragma unroll
                for (int r = 0; r < 4; ++r)
                    outp[(size_t)(r0 + r) * H_ + col] = f2bf(acc[w][mi][ni][r] * qs);
            }
        }
    }
    {
        unsigned short* vt = QKV + (size_t)2 * M_ * H_;
        int b = row0 / C_;
        int cbase = row0 % C_;
#pragma unroll
        for (int mi = 0; mi < 2; ++mi) {
            int c0 = cbase + mi * 16 + lq * 4;
#pragma unroll
            for (int ni = 0; ni < 2; ++ni) {
                int h = wcol + ni * 16 + lrow;
                __align__(8) unsigned short p[4] = {f2bf(acc[2][mi][ni][0]), f2bf(acc[2][mi][ni][1]),
                                                    f2bf(acc[2][mi][ni][2]), f2bf(acc[2][mi][ni][3])};
                *(uint2*)&vt[((size_t)b * H_ + h) * C_ + c0] = *(const uint2*)p;
            }
        }
    }
}

// ---------------- split-KV flash attention chunks ---------------------------
// grid (B, 144): blockIdx.x = batch -> XCD = b (K/V L2-resident per XCD)
__global__ __launch_bounds__(256) void attn_kernel(const unsigned short* __restrict__ QKV,
                                                   unsigned short* __restrict__ PO,
                                                   float* __restrict__ ML,
                                                   float* __restrict__ out) {
    __shared__ __align__(16) unsigned short Ks[2][64][128];
    __shared__ __align__(16) unsigned short Vt[2][128][64];
    __shared__ __align__(16) unsigned short Ps[4][16][72];

    const unsigned short* Q  = QKV;
    const unsigned short* K  = QKV + (size_t)M_ * H_;
    const unsigned short* VT = QKV + (size_t)2 * M_ * H_;

    const int tid = threadIdx.x, wid = tid >> 6, lane = tid & 63;
    const int lrow = lane & 15, lq = lane >> 4, lk = lq * 8;
    const int b = blockIdx.x;           // XCD-pinned: linear id % 8 == b
    const int rr = blockIdx.y;          // 0..143

    // decode rr -> (j, c): C(j) = j + 2q(q-1) + s*q, q=j>>2, s=j&3
    int j = 0;
#pragma unroll
    for (int jj = 1; jj < 32; ++jj) {
        int q = jj >> 2, s = jj & 3;
        if (jj + 2 * q * (q - 1) + s * q <= rr) j = jj;
    }
    const int qj = j >> 2, sj = j & 3;
    const int Cj = j + 2 * qj * (qj - 1) + sj * qj;
    const int c = rr - Cj;
    const int nch = qj + 1;
    const int t0 = c * 4;
    const int t1 = min(t0 + 4, j + 1);

    const int q0w = j * 64 + wid * 16;
    const unsigned short* Kb  = K  + (size_t)b * C_ * H_;
    const unsigned short* VTb = VT + (size_t)b * H_ * C_;
    const int qrow0 = q0w + lq * 4;

    const int krow = tid >> 4, kg = tid & 15;
    const int vrow = tid >> 3, vg = tid & 7;

    bf16x8 qf[4];
#pragma unroll
    for (int kf = 0; kf < 4; ++kf)
        qf[kf] = *(const bf16x8*)&Q[((size_t)b * C_ + q0w + lrow) * H_ + kf * 32 + lk];

    f32x4 o[8];
#pragma unroll
    for (int nf = 0; nf < 8; ++nf) o[nf] = (f32x4){0.f, 0.f, 0.f, 0.f};
    float m[4] = {-INFINITY, -INFINITY, -INFINITY, -INFINITY};
    float l[4] = {0.f, 0.f, 0.f, 0.f};

    auto STAGE = [&](int buf, int t) {
        const int kv0 = t * 64;
#pragma unroll
        for (int s = 0; s < 4; ++s) {
            int r = s * 16 + krow;
            GLOAD_LDS16(&Kb[(size_t)(kv0 + r) * H_ + ((kg ^ (r & 15)) * 8)],
                        (char*)&Ks[buf][0][0] + s * 4096 + tid * 16);
        }
#pragma unroll
        for (int s = 0; s < 4; ++s) {
            int h = s * 32 + vrow;
            GLOAD_LDS16(&VTb[(size_t)h * C_ + kv0 + ((vg ^ (h & 7)) * 8)],
                        (char*)&Vt[buf][0][0] + s * 4096 + tid * 16);
        }
    };

    STAGE(0, t0);

    for (int t = t0; t < t1; ++t) {
        const int cur = (t - t0) & 1;
        __syncthreads();
        if (t + 1 < t1) STAGE(cur ^ 1, t + 1);

        const int kv0 = t * 64;
        f32x4 s[4];
        __builtin_amdgcn_s_setprio(1);
#pragma unroll
        for (int nf = 0; nf < 4; ++nf) {
            s[nf] = (f32x4){0.f, 0.f, 0.f, 0.f};
            const int rk = nf * 16 + lrow;
#pragma unroll
            for (int kf = 0; kf < 4; ++kf) {
                bf16x8 kb = *(const bf16x8*)&Ks[cur][rk][((kf * 4 + lq) ^ (rk & 15)) * 8];
                s[nf] = __builtin_amdgcn_mfma_f32_16x16x32_bf16(qf[kf], kb, s[nf], 0, 0, 0);
            }
        }
        __builtin_amdgcn_s_setprio(0);
        bf16x8 vb[8][2];
#pragma unroll
        for (int nf = 0; nf < 8; ++nf) {
            const int h = nf * 16 + lrow;
#pragma unroll
            for (int kf2 = 0; kf2 < 2; ++kf2)
                vb[nf][kf2] = *(const bf16x8*)&Vt[cur][h][((kf2 * 4 + lq) ^ (h & 7)) * 8];
        }

        if (t == j) {
#pragma unroll
            for (int nf = 0; nf < 4; ++nf) {
                int key = kv0 + nf * 16 + lrow;
#pragma unroll
                for (int r = 0; r < 4; ++r)
                    if (key > qrow0 + r) s[nf][r] = -INFINITY;
            }
        }
        float mt[4] = {-INFINITY, -INFINITY, -INFINITY, -INFINITY};
#pragma unroll
        for (int nf = 0; nf < 4; ++nf)
#pragma unroll
            for (int r = 0; r < 4; ++r) mt[r] = fmaxf(mt[r], s[nf][r]);
#pragma unroll
        for (int r = 0; r < 4; ++r)
#pragma unroll
            for (int off = 1; off < 16; off <<= 1)
                mt[r] = fmaxf(mt[r], __shfl_xor(mt[r], off));

        float corr[4];
#pragma unroll
        for (int r = 0; r < 4; ++r) {
            float mn = fmaxf(m[r], mt[r]);
            corr[r] = __expf(m[r] - mn);
            m[r] = mn;
        }
        float ps[4] = {0.f, 0.f, 0.f, 0.f};
#pragma unroll
        for (int nf = 0; nf < 4; ++nf)
#pragma unroll
            for (int r = 0; r < 4; ++r) {
                float p = __expf(s[nf][r] - m[r]);
                ps[r] += p;
                Ps[wid][lq * 4 + r][nf * 16 + lrow] = f2bf(p);
            }
#pragma unroll
        for (int r = 0; r < 4; ++r) {
#pragma unroll
            for (int off = 1; off < 16; off <<= 1) ps[r] += __shfl_xor(ps[r], off);
            l[r] = l[r] * corr[r] + ps[r];
        }
#pragma unroll
        for (int nf = 0; nf < 8; ++nf)
#pragma unroll
            for (int r = 0; r < 4; ++r) o[nf][r] *= corr[r];

        bf16x8 pa[2];
#pragma unroll
        for (int kf2 = 0; kf2 < 2; ++kf2)
            pa[kf2] = *(const bf16x8*)&Ps[wid][lrow][kf2 * 32 + lk];
        __builtin_amdgcn_s_setprio(1);
#pragma unroll
        for (int nf = 0; nf < 8; ++nf)
#pragma unroll
            for (int kf2 = 0; kf2 < 2; ++kf2)
                o[nf] = __builtin_amdgcn_mfma_f32_16x16x32_bf16(pa[kf2], vb[nf][kf2], o[nf], 0, 0, 0);
        __builtin_amdgcn_s_setprio(0);
    }

    if (nch == 1) {       // j <= 3: single chunk, write normalized
#pragma unroll
        for (int nf = 0; nf < 8; ++nf) {
            int col = nf * 16 + lrow;
#pragma unroll
            for (int r = 0; r < 4; ++r)
                out[((size_t)b * C_ + qrow0 + r) * H_ + col] = o[nf][r] / l[r];
        }
    } else {              // partial: O (bf16, unnormalized) + m,l
        const int slot = b * SLOTS_B + rr;
        unsigned short* po = PO + (size_t)slot * 64 * 128;
        const int rl0 = wid * 16 + lq * 4;
#pragma unroll
        for (int nf = 0; nf < 8; ++nf) {
            int col = nf * 16 + lrow;
#pragma unroll
            for (int r = 0; r < 4; ++r)
                po[(size_t)(rl0 + r) * 128 + col] = f2bf(o[nf][r]);
        }
        if (lrow == 0) {
            float* ml = ML + (size_t)slot * 128;
#pragma unroll
            for (int r = 0; r < 4; ++r) {
                ml[rl0 + r] = m[r];
                ml[64 + rl0 + r] = l[r];
            }
        }
    }
}

// ---------------- combine partials for j >= 4 --------------------------------
__global__ __launch_bounds__(256) void combine_kernel(const unsigned short* __restrict__ PO,
                                                      const float* __restrict__ ML,
                                                      float* __restrict__ out) {
    const int j = blockIdx.x + 4;
    const int b = blockIdx.y;
    const int q = j >> 2, s = j & 3;
    const int Cj = j + 2 * q * (q - 1) + s * q;
    const int nch = q + 1;
    const int base = b * SLOTS_B + Cj;
    const int row = threadIdx.x >> 2;
    const int colg = (threadIdx.x & 3) * 32;

    float mstar = -INFINITY;
    for (int c = 0; c < nch; ++c)
        mstar = fmaxf(mstar, ML[(size_t)(base + c) * 128 + row]);

    float denom = 0.f;
    float acc[32];
#pragma unroll
    for (int i = 0; i < 32; ++i) acc[i] = 0.f;

    for (int c = 0; c < nch; ++c) {
        float mc = ML[(size_t)(base + c) * 128 + row];
        float lc = ML[(size_t)(base + c) * 128 + 64 + row];
        float w = __expf(mc - mstar);
        denom += w * lc;
        const unsigned short* p = PO + (size_t)(base + c) * 64 * 128 + (size_t)row * 128 + colg;
#pragma unroll
        for (int k = 0; k < 4; ++k) {
            bf16x8 v = *(const bf16x8*)&p[k * 8];
#pragma unroll
            for (int e = 0; e < 8; ++e)
                acc[k * 8 + e] += w * bf2f(((unsigned short*)&v)[e]);
        }
    }
    float inv = 1.f / denom;
    float* op = out + ((size_t)b * C_ + j * 64 + row) * H_ + colg;
#pragma unroll
    for (int k = 0; k < 8; ++k) {
        float4 st = {acc[k * 4] * inv, acc[k * 4 + 1] * inv, acc[k * 4 + 2] * inv, acc[k * 4 + 3] * inv};
        *(float4*)&op[k * 4] = st;
    }
}

extern "C" void kernel_launch(void* const* d_in, const int* in_sizes, int n_in,
                              void* d_out, int out_size, void* d_ws, size_t ws_size,
                              hipStream_t stream) {
    const float* x  = (const float*)d_in[0];
    const float* Wq = (const float*)d_in[1];
    const float* Wk = (const float*)d_in[2];
    const float* Wv = (const float*)d_in[3];
    float* out = (float*)d_out;

    // ws layout (~31.4 MB total):
    unsigned short* WT2 = (unsigned short*)d_ws;                       // 768 KB
    unsigned short* QKV = WT2 + (size_t)3 * H_ * E_;                   // 12 MB (Q, K, V^T)
    unsigned short* PO  = QKV + (size_t)3 * M_ * H_;                   // 18 MB partial O
    float*          ML  = (float*)(PO + (size_t)8 * SLOTS_B * 64 * 128); // 576 KB m,l

    wt2_kernel<<<dim3(E_ / 8 * H_ / 256, 3), 256, 0, stream>>>(Wq, Wk, Wv, WT2);
    proj_kernel<<<dim3(M_ / 32), 256, 0, stream>>>(x, WT2, QKV);
    attn_kernel<<<dim3(B_, SLOTS_B), 256, 0, stream>>>(QKV, PO, ML, out);
    combine_kernel<<<dim3(28, B_), 256, 0, stream>>>(PO, ML, out);
}